// Round 1
// baseline (3281.653 us; speedup 1.0000x reference)
//
#include <hip/hip_runtime.h>

// 2-layer LSTM (B=2048, T=512, in=4, H=64) + Linear(64,64) + tanh, fully fused.
// Block = 256 threads = 4 waves, owns NB=4 batch elements for all 512 steps.
// Thread t owns gate-row t (of 4H=256) for BOTH layers; its 192 weight floats
// (w_hh0 row, w_ih1 row, w_hh1 row) live in VGPRs for the whole kernel.
// h0/h1 state vectors round-trip through LDS each step (broadcast reads).

#define HID 64
#define TSTEPS 512
#define NB 4
#define BLK 256

__device__ __forceinline__ float sigf(float x) {
    // safe: x << 0 -> exp(+inf) -> 1/inf = 0; x >> 0 -> 1.
    return 1.0f / (1.0f + __expf(-x));
}
__device__ __forceinline__ float tanh_safe(float x) {
    // tanh via exp of NON-POSITIVE argument only -> never overflows/NaNs.
    float ax = fabsf(x);
    float e  = __expf(-2.0f * ax);          // in (0, 1]
    float t  = (1.0f - e) / (1.0f + e);     // in [0, 1)
    return copysignf(t, x);
}

__global__ __launch_bounds__(BLK, 2) void lstm_fused(
    const float* __restrict__ x,      // (2048, 512, 4)
    const float* __restrict__ w_ih0,  // (256, 4)
    const float* __restrict__ w_hh0,  // (256, 64)
    const float* __restrict__ b_ih0,  // (256,)
    const float* __restrict__ b_hh0,  // (256,)
    const float* __restrict__ w_ih1,  // (256, 64)
    const float* __restrict__ w_hh1,  // (256, 64)
    const float* __restrict__ b_ih1,  // (256,)
    const float* __restrict__ b_hh1,  // (256,)
    const float* __restrict__ fc_w,   // (64, 64)
    const float* __restrict__ fc_b,   // (64,)
    float* __restrict__ out)          // (2048, 64)
{
    __shared__ float pre[NB * 256];   // gate preacts, layout [b][gate] (2-way bank max)
    __shared__ float h0s[NB * HID];   // layer-0 h, layout [b][u]
    __shared__ float h1s[NB * HID];   // layer-1 h, layout [b][u]

    const int t   = threadIdx.x;            // gate row 0..255
    const int b0g = blockIdx.x * NB;        // global batch base

    // ---- weights into registers (held for all 512 steps) ----
    float whh0r[HID], wih1r[HID], whh1r[HID];
    {
        const float4* p0 = (const float4*)(w_hh0 + t * HID);
        const float4* p1 = (const float4*)(w_ih1 + t * HID);
        const float4* p2 = (const float4*)(w_hh1 + t * HID);
        #pragma unroll
        for (int kk = 0; kk < HID / 4; ++kk) {
            ((float4*)whh0r)[kk] = p0[kk];
            ((float4*)wih1r)[kk] = p1[kk];
            ((float4*)whh1r)[kk] = p2[kk];
        }
    }
    float wih0r[4];
    {
        const float4 w4 = *(const float4*)(w_ih0 + t * 4);
        wih0r[0] = w4.x; wih0r[1] = w4.y; wih0r[2] = w4.z; wih0r[3] = w4.w;
    }
    const float bias0 = b_ih0[t] + b_hh0[t];
    const float bias1 = b_ih1[t] + b_hh1[t];

    // elementwise ownership: thread t updates (unit uu, batch bb)
    const int uu = t & (HID - 1);
    const int bb = t >> 6;
    float c0 = 0.0f, c1 = 0.0f;

    // zero initial h state (NB*HID == BLK)
    h0s[t] = 0.0f;
    h1s[t] = 0.0f;
    __syncthreads();

    #pragma unroll 1
    for (int step = 0; step < TSTEPS; ++step) {
        // ---- phase 1: layer-0 gate preacts (reads h0s of prev step) ----
        {
            float acc[NB];
            #pragma unroll
            for (int b = 0; b < NB; ++b) {
                // x address is wave-uniform -> scalar load
                const float4 xv = *(const float4*)(x + ((size_t)(b0g + b) * TSTEPS + step) * 4);
                float a = bias0 + xv.x * wih0r[0] + xv.y * wih0r[1]
                                + xv.z * wih0r[2] + xv.w * wih0r[3];
                const float4* hp = (const float4*)(h0s + b * HID);
                #pragma unroll
                for (int kk = 0; kk < HID / 4; ++kk) {
                    const float4 h = hp[kk];  // wave-uniform broadcast read
                    a += h.x * whh0r[4 * kk + 0] + h.y * whh0r[4 * kk + 1]
                       + h.z * whh0r[4 * kk + 2] + h.w * whh0r[4 * kk + 3];
                }
                acc[b] = a;
            }
            #pragma unroll
            for (int b = 0; b < NB; ++b) pre[b * 256 + t] = acc[b];
        }
        __syncthreads();

        // ---- phase 2: layer-0 elementwise; write new h0 ----
        {
            const float gi = sigf(pre[bb * 256 + uu]);
            const float gf = sigf(pre[bb * 256 + 64 + uu]);
            const float gg = tanh_safe(pre[bb * 256 + 128 + uu]);
            const float go = sigf(pre[bb * 256 + 192 + uu]);
            c0 = gf * c0 + gi * gg;
            h0s[bb * HID + uu] = go * tanh_safe(c0);
        }
        __syncthreads();

        // ---- phase 3: layer-1 gate preacts (reads NEW h0s, prev h1s) ----
        {
            float acc[NB];
            #pragma unroll
            for (int b = 0; b < NB; ++b) {
                float a = bias1;
                const float4* hp0 = (const float4*)(h0s + b * HID);
                const float4* hp1 = (const float4*)(h1s + b * HID);
                #pragma unroll
                for (int kk = 0; kk < HID / 4; ++kk) {
                    const float4 ha = hp0[kk];
                    const float4 hb = hp1[kk];
                    a += ha.x * wih1r[4 * kk + 0] + ha.y * wih1r[4 * kk + 1]
                       + ha.z * wih1r[4 * kk + 2] + ha.w * wih1r[4 * kk + 3];
                    a += hb.x * whh1r[4 * kk + 0] + hb.y * whh1r[4 * kk + 1]
                       + hb.z * whh1r[4 * kk + 2] + hb.w * whh1r[4 * kk + 3];
                }
                acc[b] = a;
            }
            #pragma unroll
            for (int b = 0; b < NB; ++b) pre[b * 256 + t] = acc[b];
        }
        __syncthreads();

        // ---- phase 4: layer-1 elementwise; write new h1 ----
        {
            const float gi = sigf(pre[bb * 256 + uu]);
            const float gf = sigf(pre[bb * 256 + 64 + uu]);
            const float gg = tanh_safe(pre[bb * 256 + 128 + uu]);
            const float go = sigf(pre[bb * 256 + 192 + uu]);
            c1 = gf * c1 + gi * gg;
            h1s[bb * HID + uu] = go * tanh_safe(c1);
        }
        __syncthreads();
    }

    // ---- epilogue: out[b][u] = tanh(h1 . fc_w[u] + fc_b[u]) ----
    {
        float a = fc_b[uu];
        const float4* hp = (const float4*)(h1s + bb * HID);
        const float4* wp = (const float4*)(fc_w + uu * HID);
        #pragma unroll
        for (int kk = 0; kk < HID / 4; ++kk) {
            const float4 h = hp[kk];
            const float4 w = wp[kk];
            a += h.x * w.x + h.y * w.y + h.z * w.z + h.w * w.w;
        }
        out[(size_t)(b0g + bb) * HID + uu] = tanh_safe(a);
    }
}

extern "C" void kernel_launch(void* const* d_in, const int* in_sizes, int n_in,
                              void* d_out, int out_size, void* d_ws, size_t ws_size,
                              hipStream_t stream) {
    const float* x     = (const float*)d_in[0];
    const float* w_ih0 = (const float*)d_in[1];
    const float* w_hh0 = (const float*)d_in[2];
    const float* b_ih0 = (const float*)d_in[3];
    const float* b_hh0 = (const float*)d_in[4];
    const float* w_ih1 = (const float*)d_in[5];
    const float* w_hh1 = (const float*)d_in[6];
    const float* b_ih1 = (const float*)d_in[7];
    const float* b_hh1 = (const float*)d_in[8];
    const float* fc_w  = (const float*)d_in[9];
    const float* fc_b  = (const float*)d_in[10];
    float* out = (float*)d_out;

    const int B = in_sizes[0] / (TSTEPS * 4);   // 2048
    lstm_fused<<<dim3(B / NB), dim3(BLK), 0, stream>>>(
        x, w_ih0, w_hh0, b_ih0, b_hh0, w_ih1, w_hh1, b_ih1, b_hh1, fc_w, fc_b, out);
}

// Round 2
// 988.748 us; speedup vs baseline: 3.3190x; 3.3190x over previous
//
#include <hip/hip_runtime.h>

// 2-layer LSTM (B=2048,T=512,in=4,H=64) + FC + tanh via MFMA f16.
// Grid = 256 blocks x 256 threads (4 waves). Block owns MB=8 batches (M-tile
// rows 8..15 padded/garbage-but-finite). Wave w owns N-tiles {w,w+4,w+8,w+12}
// of the 4H=256 gate dim, so unit u = 16w+(lane&15) has all four gates
// (i,f,g,o) in acc tiles 0..3 of the SAME lane -> elementwise is
// register-local and c-state stays in VGPRs for all 512 steps.
// Weights live as B-fragments (112 VGPR/lane, loaded once). h state round-
// trips LDS as f16 (parity double-buffered), 2 barriers/step.

#define HID 64
#define TSTEPS 512
#define MB 8
#define BLK 256
#define HSTR 72   // f16 row stride for 16-row h tiles: 144 B, keeps b128 reads
                  // 16B-aligned (72*2 % 16 == 0) and bank pattern ~contiguous

typedef _Float16 f16;
typedef _Float16 half8 __attribute__((ext_vector_type(8)));
typedef _Float16 half4 __attribute__((ext_vector_type(4)));
typedef float f32x4 __attribute__((ext_vector_type(4)));

__device__ __forceinline__ float sigf(float x) {
    return 1.0f / (1.0f + __expf(-x));
}
__device__ __forceinline__ float tanh_safe(float x) {
    float ax = fabsf(x);
    float e  = __expf(-2.0f * ax);        // exp of non-positive arg: no overflow
    float t  = (1.0f - e) / (1.0f + e);
    return copysignf(t, x);
}

__global__ __launch_bounds__(BLK, 1) void lstm_mfma(
    const float* __restrict__ x,      // (2048, 512, 4)
    const float* __restrict__ w_ih0,  // (256, 4)
    const float* __restrict__ w_hh0,  // (256, 64)
    const float* __restrict__ b_ih0,  // (256,)
    const float* __restrict__ b_hh0,  // (256,)
    const float* __restrict__ w_ih1,  // (256, 64)
    const float* __restrict__ w_hh1,  // (256, 64)
    const float* __restrict__ b_ih1,  // (256,)
    const float* __restrict__ b_hh1,  // (256,)
    const float* __restrict__ fc_w,   // (64, 64)
    const float* __restrict__ fc_b,   // (64,)
    float* __restrict__ out)          // (2048, 64)
{
    __shared__ f16 xs[TSTEPS * MB * 4];        // [t][m][4]  32 KB
    __shared__ f16 hs0[2][16 * HSTR];          // parity-double-buffered h0
    __shared__ f16 hs1[2][16 * HSTR];          // parity-double-buffered h1

    const int tid  = threadIdx.x;
    const int w    = tid >> 6;        // wave 0..3
    const int l    = tid & 63;
    const int quad = l >> 4;          // 0..3
    const int l15  = l & 15;
    const int b0   = blockIdx.x * MB;
    const int u    = w * 16 + l15;    // unit owned in elementwise phase

    // ---- stage x into LDS as f16: xs[t][m][0..3] ----
    for (int it = tid; it < MB * TSTEPS; it += BLK) {
        const int m = it >> 9;        // 0..7
        const int t = it & 511;
        const float4 v = *((const float4*)x + (size_t)(b0 + m) * TSTEPS + t);
        half4 hv = { (f16)v.x, (f16)v.y, (f16)v.z, (f16)v.w };
        *(half4*)(xs + (t * MB + m) * 4) = hv;
    }
    // zero initial h state (both parities)
    for (int it = tid; it < 16 * HSTR; it += BLK) {
        hs0[0][it] = (f16)0.f; hs0[1][it] = (f16)0.f;
        hs1[0][it] = (f16)0.f; hs1[1][it] = (f16)0.f;
    }

    // ---- B-fragments (held in VGPRs for all 512 steps) ----
    // B-frag layout: lane holds B[k = quad*8+j][n = tile_base + l15], j=0..7
    half8 P0[4];                 // w_ih0^T padded to K=32 (k<4 real, rest 0)
    half8 W0[4][2];              // w_hh0^T, K=64 -> 2 ksteps
    half8 W1i[4][2];             // w_ih1^T
    half8 W1h[4][2];             // w_hh1^T
    float b0r[4], b1r[4];

    #pragma unroll
    for (int ti = 0; ti < 4; ++ti) {
        const int n = (w + 4 * ti) * 16 + l15;   // gate row index
        half8 pz = { (f16)0.f,(f16)0.f,(f16)0.f,(f16)0.f,
                     (f16)0.f,(f16)0.f,(f16)0.f,(f16)0.f };
        if (quad == 0) {
            const float4 v = *(const float4*)(w_ih0 + n * 4);
            pz[0] = (f16)v.x; pz[1] = (f16)v.y; pz[2] = (f16)v.z; pz[3] = (f16)v.w;
        }
        P0[ti] = pz;
        #pragma unroll
        for (int ks = 0; ks < 2; ++ks) {
            const int ko = ks * 32 + quad * 8;
            const float4 a = *(const float4*)(w_hh0 + n * HID + ko);
            const float4 b = *(const float4*)(w_hh0 + n * HID + ko + 4);
            half8 f = { (f16)a.x,(f16)a.y,(f16)a.z,(f16)a.w,
                        (f16)b.x,(f16)b.y,(f16)b.z,(f16)b.w };
            W0[ti][ks] = f;
            const float4 c = *(const float4*)(w_ih1 + n * HID + ko);
            const float4 d = *(const float4*)(w_ih1 + n * HID + ko + 4);
            half8 g = { (f16)c.x,(f16)c.y,(f16)c.z,(f16)c.w,
                        (f16)d.x,(f16)d.y,(f16)d.z,(f16)d.w };
            W1i[ti][ks] = g;
            const float4 e = *(const float4*)(w_hh1 + n * HID + ko);
            const float4 h = *(const float4*)(w_hh1 + n * HID + ko + 4);
            half8 q = { (f16)e.x,(f16)e.y,(f16)e.z,(f16)e.w,
                        (f16)h.x,(f16)h.y,(f16)h.z,(f16)h.w };
            W1h[ti][ks] = q;
        }
        b0r[ti] = b_ih0[n] + b_hh0[n];
        b1r[ti] = b_ih1[n] + b_hh1[n];
    }

    f32x4 c0 = { 0.f, 0.f, 0.f, 0.f };
    f32x4 c1 = { 0.f, 0.f, 0.f, 0.f };
    __syncthreads();

    int bufp = 0;
    #pragma unroll 1
    for (int t = 0; t < TSTEPS; ++t) {
        const f16* h0p = hs0[bufp];
        const f16* h1p = hs1[bufp];
        f16* h0n = hs0[bufp ^ 1];
        f16* h1n = hs1[bufp ^ 1];

        // A-fragments of previous state: A[m=l15][k=quad*8+j]
        const half8 a0lo = *(const half8*)(h0p + l15 * HSTR + quad * 8);
        const half8 a0hi = *(const half8*)(h0p + l15 * HSTR + 32 + quad * 8);
        const half8 a1lo = *(const half8*)(h1p + l15 * HSTR + quad * 8);
        const half8 a1hi = *(const half8*)(h1p + l15 * HSTR + 32 + quad * 8);

        // x fragment (K padded to 32; rows m>=8 alias m-8: finite garbage)
        const half4 xv = *(const half4*)(xs + (t * MB + (l15 & 7)) * 4);
        half8 ax = { (f16)0.f,(f16)0.f,(f16)0.f,(f16)0.f,
                     (f16)0.f,(f16)0.f,(f16)0.f,(f16)0.f };
        if (quad == 0) { ax[0] = xv[0]; ax[1] = xv[1]; ax[2] = xv[2]; ax[3] = xv[3]; }

        // ---- layer 0 matmul: gates = [x|pad]@P0 + h0@W0 + bias ----
        f32x4 g0, g1, g2, g3;
        {
            f32x4 acc = { b0r[0], b0r[0], b0r[0], b0r[0] };
            acc = __builtin_amdgcn_mfma_f32_16x16x32_f16(ax,   P0[0],    acc, 0, 0, 0);
            acc = __builtin_amdgcn_mfma_f32_16x16x32_f16(a0lo, W0[0][0], acc, 0, 0, 0);
            g0  = __builtin_amdgcn_mfma_f32_16x16x32_f16(a0hi, W0[0][1], acc, 0, 0, 0);
        }
        {
            f32x4 acc = { b0r[1], b0r[1], b0r[1], b0r[1] };
            acc = __builtin_amdgcn_mfma_f32_16x16x32_f16(ax,   P0[1],    acc, 0, 0, 0);
            acc = __builtin_amdgcn_mfma_f32_16x16x32_f16(a0lo, W0[1][0], acc, 0, 0, 0);
            g1  = __builtin_amdgcn_mfma_f32_16x16x32_f16(a0hi, W0[1][1], acc, 0, 0, 0);
        }
        {
            f32x4 acc = { b0r[2], b0r[2], b0r[2], b0r[2] };
            acc = __builtin_amdgcn_mfma_f32_16x16x32_f16(ax,   P0[2],    acc, 0, 0, 0);
            acc = __builtin_amdgcn_mfma_f32_16x16x32_f16(a0lo, W0[2][0], acc, 0, 0, 0);
            g2  = __builtin_amdgcn_mfma_f32_16x16x32_f16(a0hi, W0[2][1], acc, 0, 0, 0);
        }
        {
            f32x4 acc = { b0r[3], b0r[3], b0r[3], b0r[3] };
            acc = __builtin_amdgcn_mfma_f32_16x16x32_f16(ax,   P0[3],    acc, 0, 0, 0);
            acc = __builtin_amdgcn_mfma_f32_16x16x32_f16(a0lo, W0[3][0], acc, 0, 0, 0);
            g3  = __builtin_amdgcn_mfma_f32_16x16x32_f16(a0hi, W0[3][1], acc, 0, 0, 0);
        }

        // ---- layer 0 elementwise: C/D layout row m = quad*4+r, col u ----
        #pragma unroll
        for (int r = 0; r < 4; ++r) {
            const float gi = sigf(g0[r]);
            const float gf = sigf(g1[r]);
            const float gg = tanh_safe(g2[r]);
            const float go = sigf(g3[r]);
            const float c = gf * c0[r] + gi * gg;
            c0[r] = c;
            h0n[(quad * 4 + r) * HSTR + u] = (f16)(go * tanh_safe(c));
        }
        __syncthreads();

        // new h0 fragments
        const half8 b0lo = *(const half8*)(h0n + l15 * HSTR + quad * 8);
        const half8 b0hi = *(const half8*)(h0n + l15 * HSTR + 32 + quad * 8);

        // ---- layer 1 matmul: gates = h0new@W1i + h1@W1h + bias ----
        {
            f32x4 acc = { b1r[0], b1r[0], b1r[0], b1r[0] };
            acc = __builtin_amdgcn_mfma_f32_16x16x32_f16(b0lo, W1i[0][0], acc, 0, 0, 0);
            acc = __builtin_amdgcn_mfma_f32_16x16x32_f16(b0hi, W1i[0][1], acc, 0, 0, 0);
            acc = __builtin_amdgcn_mfma_f32_16x16x32_f16(a1lo, W1h[0][0], acc, 0, 0, 0);
            g0  = __builtin_amdgcn_mfma_f32_16x16x32_f16(a1hi, W1h[0][1], acc, 0, 0, 0);
        }
        {
            f32x4 acc = { b1r[1], b1r[1], b1r[1], b1r[1] };
            acc = __builtin_amdgcn_mfma_f32_16x16x32_f16(b0lo, W1i[1][0], acc, 0, 0, 0);
            acc = __builtin_amdgcn_mfma_f32_16x16x32_f16(b0hi, W1i[1][1], acc, 0, 0, 0);
            acc = __builtin_amdgcn_mfma_f32_16x16x32_f16(a1lo, W1h[1][0], acc, 0, 0, 0);
            g1  = __builtin_amdgcn_mfma_f32_16x16x32_f16(a1hi, W1h[1][1], acc, 0, 0, 0);
        }
        {
            f32x4 acc = { b1r[2], b1r[2], b1r[2], b1r[2] };
            acc = __builtin_amdgcn_mfma_f32_16x16x32_f16(b0lo, W1i[2][0], acc, 0, 0, 0);
            acc = __builtin_amdgcn_mfma_f32_16x16x32_f16(b0hi, W1i[2][1], acc, 0, 0, 0);
            acc = __builtin_amdgcn_mfma_f32_16x16x32_f16(a1lo, W1h[2][0], acc, 0, 0, 0);
            g2  = __builtin_amdgcn_mfma_f32_16x16x32_f16(a1hi, W1h[2][1], acc, 0, 0, 0);
        }
        {
            f32x4 acc = { b1r[3], b1r[3], b1r[3], b1r[3] };
            acc = __builtin_amdgcn_mfma_f32_16x16x32_f16(b0lo, W1i[3][0], acc, 0, 0, 0);
            acc = __builtin_amdgcn_mfma_f32_16x16x32_f16(b0hi, W1i[3][1], acc, 0, 0, 0);
            acc = __builtin_amdgcn_mfma_f32_16x16x32_f16(a1lo, W1h[3][0], acc, 0, 0, 0);
            g3  = __builtin_amdgcn_mfma_f32_16x16x32_f16(a1hi, W1h[3][1], acc, 0, 0, 0);
        }

        // ---- layer 1 elementwise ----
        #pragma unroll
        for (int r = 0; r < 4; ++r) {
            const float gi = sigf(g0[r]);
            const float gf = sigf(g1[r]);
            const float gg = tanh_safe(g2[r]);
            const float go = sigf(g3[r]);
            const float c = gf * c1[r] + gi * gg;
            c1[r] = c;
            h1n[(quad * 4 + r) * HSTR + u] = (f16)(go * tanh_safe(c));
        }
        __syncthreads();
        bufp ^= 1;
    }

    // ---- epilogue: out[b][v] = tanh(h1 . fc_w[v] + fc_b[v]) ----
    const f16* h1f = hs1[bufp];   // parity of the last write
    const int v  = tid & 63;
    const int mg = tid >> 6;
    #pragma unroll
    for (int pass = 0; pass < 2; ++pass) {
        const int m = mg + 4 * pass;
        float a = fc_b[v];
        const float4* wp = (const float4*)(fc_w + v * HID);
        #pragma unroll
        for (int kk = 0; kk < HID / 4; ++kk) {
            const float4 wv = wp[kk];
            a += (float)h1f[m * HSTR + kk * 4 + 0] * wv.x
               + (float)h1f[m * HSTR + kk * 4 + 1] * wv.y
               + (float)h1f[m * HSTR + kk * 4 + 2] * wv.z
               + (float)h1f[m * HSTR + kk * 4 + 3] * wv.w;
        }
        out[(size_t)(b0 + m) * HID + v] = tanh_safe(a);
    }
}

extern "C" void kernel_launch(void* const* d_in, const int* in_sizes, int n_in,
                              void* d_out, int out_size, void* d_ws, size_t ws_size,
                              hipStream_t stream) {
    const float* x     = (const float*)d_in[0];
    const float* w_ih0 = (const float*)d_in[1];
    const float* w_hh0 = (const float*)d_in[2];
    const float* b_ih0 = (const float*)d_in[3];
    const float* b_hh0 = (const float*)d_in[4];
    const float* w_ih1 = (const float*)d_in[5];
    const float* w_hh1 = (const float*)d_in[6];
    const float* b_ih1 = (const float*)d_in[7];
    const float* b_hh1 = (const float*)d_in[8];
    const float* fc_w  = (const float*)d_in[9];
    const float* fc_b  = (const float*)d_in[10];
    float* out = (float*)d_out;

    const int B = in_sizes[0] / (TSTEPS * 4);   // 2048
    lstm_mfma<<<dim3(B / MB), dim3(BLK), 0, stream>>>(
        x, w_ih0, w_hh0, b_ih0, b_hh0, w_ih1, w_hh1, b_ih1, b_hh1, fc_w, fc_b, out);
}

// Round 3
// 495.804 us; speedup vs baseline: 6.6188x; 1.9942x over previous
//
#include <hip/hip_runtime.h>

// 2-layer LSTM (B=2048,T=512,in=4,H=64) + FC + tanh, MFMA f16, layer-pipelined.
// Grid = 256 blocks x 256 threads (4 waves), block owns MB=8 real batches.
// M rows 0-7  = layer 0 at step t   (batch m)
// M rows 8-15 = layer 1 at step t-1 (batch m-8)  -- 1-step pipeline skew, so
// ALL 16 MFMA rows are real work and elementwise has zero padding waste.
// K stacked (224 = 7 chunks of 32): [x-pad | h0@W0 | h0@W1i | h1@W1h].
// Row-group zeroing is structural: h0a has h0 in rows 0-7 / zeros in 8-15,
// h0b has zeros/h0, h1b has zeros/h1 -- rows never written stay zero.
// One barrier per round (reads parity p^1, writes parity p). 513 rounds.
// Activations use v_rcp_f32 instead of IEEE division (the round-2 VALU hog).

#define HID 64
#define TSTEPS 512
#define MB 8
#define BLK 256
#define HSTR 72   // f16 row stride: 144 B keeps ds_read_b128 16B-aligned

typedef _Float16 f16;
typedef _Float16 half8 __attribute__((ext_vector_type(8)));
typedef _Float16 half4 __attribute__((ext_vector_type(4)));
typedef float f32x4 __attribute__((ext_vector_type(4)));

__device__ __forceinline__ float sigf(float x) {
    // 1/(1+e^-x); e^-x -> +inf for x<<0 gives rcp(inf)=0: safe.
    const float e = __expf(-x);
    return __builtin_amdgcn_rcpf(1.0f + e);
}
__device__ __forceinline__ float tanh_safe(float x) {
    // exp of non-positive arg only: never overflows.
    const float ax = fabsf(x);
    const float e  = __expf(-2.0f * ax);
    const float t  = (1.0f - e) * __builtin_amdgcn_rcpf(1.0f + e);
    return copysignf(t, x);
}

__global__ __launch_bounds__(BLK, 1) void lstm_mfma(
    const float* __restrict__ x,      // (2048, 512, 4)
    const float* __restrict__ w_ih0,  // (256, 4)
    const float* __restrict__ w_hh0,  // (256, 64)
    const float* __restrict__ b_ih0,  // (256,)
    const float* __restrict__ b_hh0,  // (256,)
    const float* __restrict__ w_ih1,  // (256, 64)
    const float* __restrict__ w_hh1,  // (256, 64)
    const float* __restrict__ b_ih1,  // (256,)
    const float* __restrict__ b_hh1,  // (256,)
    const float* __restrict__ fc_w,   // (64, 64)
    const float* __restrict__ fc_b,   // (64,)
    float* __restrict__ out)          // (2048, 64)
{
    __shared__ f16 xs[TSTEPS * MB * 4];    // [t][m][4]  32 KB
    __shared__ f16 h0a[2][16 * HSTR];      // h0 rows 0-7, ZERO rows 8-15
    __shared__ f16 h0b[2][16 * HSTR];      // ZERO rows 0-7, h0 rows 8-15
    __shared__ f16 h1b[2][16 * HSTR];      // ZERO rows 0-7, h1 rows 8-15
    __shared__ f16 dump[64];               // scrap target for masked 2nd write

    const int tid  = threadIdx.x;
    const int w    = tid >> 6;        // wave 0..3
    const int l    = tid & 63;
    const int quad = l >> 4;          // 0..3
    const int l15  = l & 15;
    const int b0   = blockIdx.x * MB;
    const int u    = w * 16 + l15;    // unit owned in elementwise phase

    // ---- stage x into LDS as f16 ----
    for (int it = tid; it < MB * TSTEPS; it += BLK) {
        const int m = it >> 9;        // 0..7
        const int t = it & 511;
        const float4 v = *((const float4*)x + (size_t)(b0 + m) * TSTEPS + t);
        half4 hv = { (f16)v.x, (f16)v.y, (f16)v.z, (f16)v.w };
        *(half4*)(xs + (t * MB + m) * 4) = hv;
    }
    // zero all h buffers (both parities); complementary halves stay zero forever
    for (int it = tid; it < 16 * HSTR; it += BLK) {
        h0a[0][it] = (f16)0.f; h0a[1][it] = (f16)0.f;
        h0b[0][it] = (f16)0.f; h0b[1][it] = (f16)0.f;
        h1b[0][it] = (f16)0.f; h1b[1][it] = (f16)0.f;
    }

    // ---- B-fragments: 7 K-chunks x 4 N-tiles, held for the whole kernel ----
    // B[k=quad*8+j][n=tile*16+l15]; chunk0=x-proj(pad), 1-2=W0, 3-4=W1i, 5-6=W1h
    half8 Bf[4][7];
    float biasr[4];
    #pragma unroll
    for (int ti = 0; ti < 4; ++ti) {
        const int n = (w + 4 * ti) * 16 + l15;   // gate row index
        half8 pz = { (f16)0.f,(f16)0.f,(f16)0.f,(f16)0.f,
                     (f16)0.f,(f16)0.f,(f16)0.f,(f16)0.f };
        if (quad == 0) {
            const float4 v = *(const float4*)(w_ih0 + n * 4);
            pz[0] = (f16)v.x; pz[1] = (f16)v.y; pz[2] = (f16)v.z; pz[3] = (f16)v.w;
        }
        Bf[ti][0] = pz;
        #pragma unroll
        for (int ks = 0; ks < 2; ++ks) {
            const int ko = ks * 32 + quad * 8;
            const float4 a = *(const float4*)(w_hh0 + n * HID + ko);
            const float4 b = *(const float4*)(w_hh0 + n * HID + ko + 4);
            Bf[ti][1 + ks] = (half8){ (f16)a.x,(f16)a.y,(f16)a.z,(f16)a.w,
                                      (f16)b.x,(f16)b.y,(f16)b.z,(f16)b.w };
            const float4 c = *(const float4*)(w_ih1 + n * HID + ko);
            const float4 d = *(const float4*)(w_ih1 + n * HID + ko + 4);
            Bf[ti][3 + ks] = (half8){ (f16)c.x,(f16)c.y,(f16)c.z,(f16)c.w,
                                      (f16)d.x,(f16)d.y,(f16)d.z,(f16)d.w };
            const float4 e = *(const float4*)(w_hh1 + n * HID + ko);
            const float4 h = *(const float4*)(w_hh1 + n * HID + ko + 4);
            Bf[ti][5 + ks] = (half8){ (f16)e.x,(f16)e.y,(f16)e.z,(f16)e.w,
                                      (f16)h.x,(f16)h.y,(f16)h.z,(f16)h.w };
        }
        // rows quad*4+r: quads 0-1 are layer-0 cells, quads 2-3 layer-1 cells
        biasr[ti] = (quad < 2) ? (b_ih0[n] + b_hh0[n]) : (b_ih1[n] + b_hh1[n]);
    }

    f32x4 cst = { 0.f, 0.f, 0.f, 0.f };   // c0 for quads 0-1, c1 for quads 2-3
    __syncthreads();

    #pragma unroll 1
    for (int r = 0; r <= TSTEPS; ++r) {    // 513 rounds (pipeline fill/drain)
        const int pr = r & 1;
        const int pv = pr ^ 1;
        const int t  = (r < TSTEPS) ? r : (TSTEPS - 1);  // round 512: garbage, unread

        // A-fragments: A[m=l15][k=quad*8+j]; zero halves are structural
        const half8 a1 = *(const half8*)(h0a[pv] + l15 * HSTR + quad * 8);
        const half8 a2 = *(const half8*)(h0a[pv] + l15 * HSTR + 32 + quad * 8);
        const half8 a3 = *(const half8*)(h0b[pv] + l15 * HSTR + quad * 8);
        const half8 a4 = *(const half8*)(h0b[pv] + l15 * HSTR + 32 + quad * 8);
        const half8 a5 = *(const half8*)(h1b[pv] + l15 * HSTR + quad * 8);
        const half8 a6 = *(const half8*)(h1b[pv] + l15 * HSTR + 32 + quad * 8);

        // x chunk: rows <8, k<4 only
        const half4 xv = *(const half4*)(xs + (t * MB + (l15 & 7)) * 4);
        half8 ax = { (f16)0.f,(f16)0.f,(f16)0.f,(f16)0.f,
                     (f16)0.f,(f16)0.f,(f16)0.f,(f16)0.f };
        if ((quad == 0) && (l15 < 8)) {
            ax[0] = xv[0]; ax[1] = xv[1]; ax[2] = xv[2]; ax[3] = xv[3];
        }

        f32x4 g[4];
        #pragma unroll
        for (int ti = 0; ti < 4; ++ti) {
            f32x4 acc = { biasr[ti], biasr[ti], biasr[ti], biasr[ti] };
            acc   = __builtin_amdgcn_mfma_f32_16x16x32_f16(ax, Bf[ti][0], acc, 0, 0, 0);
            acc   = __builtin_amdgcn_mfma_f32_16x16x32_f16(a1, Bf[ti][1], acc, 0, 0, 0);
            acc   = __builtin_amdgcn_mfma_f32_16x16x32_f16(a2, Bf[ti][2], acc, 0, 0, 0);
            acc   = __builtin_amdgcn_mfma_f32_16x16x32_f16(a3, Bf[ti][3], acc, 0, 0, 0);
            acc   = __builtin_amdgcn_mfma_f32_16x16x32_f16(a4, Bf[ti][4], acc, 0, 0, 0);
            acc   = __builtin_amdgcn_mfma_f32_16x16x32_f16(a5, Bf[ti][5], acc, 0, 0, 0);
            g[ti] = __builtin_amdgcn_mfma_f32_16x16x32_f16(a6, Bf[ti][6], acc, 0, 0, 0);
        }

        // round 0: layer-1 rows compute step -1 -> squash state & output to 0
        const float keep = ((r == 0) && (quad >= 2)) ? 0.f : 1.f;
        const bool  is0  = (quad < 2);

        #pragma unroll
        for (int rr = 0; rr < 4; ++rr) {
            const int m = quad * 4 + rr;            // C/D row
            const float gi = sigf(g[0][rr]);
            const float gf = sigf(g[1][rr]);
            const float gg = tanh_safe(g[2][rr]);
            const float go = sigf(g[3][rr]);
            float c = gf * cst[rr] + gi * gg;
            c *= keep;
            cst[rr] = c;
            const f16 hf = (f16)(keep * go * tanh_safe(c));
            // layer0: write h0a[m] and mirror h0b[m+8]; layer1: write h1b[m]
            f16* pA = is0 ? &h0a[pr][m * HSTR + u] : &h1b[pr][m * HSTR + u];
            f16* pB = is0 ? &h0b[pr][(m + 8) * HSTR + u] : &dump[l];
            *pA = hf;
            *pB = hf;
        }
        __syncthreads();
    }

    // ---- epilogue: final h1(T-1) sits in h1b[parity of round 512 = 0] rows 8-15 ----
    const f16* h1f = h1b[0];
    const int v  = tid & 63;
    const int mg = tid >> 6;
    #pragma unroll
    for (int pass = 0; pass < 2; ++pass) {
        const int m = mg + 4 * pass;                // 0..7
        float a = fc_b[v];
        const float4* wp = (const float4*)(fc_w + v * HID);
        #pragma unroll
        for (int kk = 0; kk < HID / 4; ++kk) {
            const float4 wv = wp[kk];
            a += (float)h1f[(8 + m) * HSTR + kk * 4 + 0] * wv.x
               + (float)h1f[(8 + m) * HSTR + kk * 4 + 1] * wv.y
               + (float)h1f[(8 + m) * HSTR + kk * 4 + 2] * wv.z
               + (float)h1f[(8 + m) * HSTR + kk * 4 + 3] * wv.w;
        }
        out[(size_t)(b0 + m) * HID + v] = tanh_safe(a);
    }
}

extern "C" void kernel_launch(void* const* d_in, const int* in_sizes, int n_in,
                              void* d_out, int out_size, void* d_ws, size_t ws_size,
                              hipStream_t stream) {
    const float* x     = (const float*)d_in[0];
    const float* w_ih0 = (const float*)d_in[1];
    const float* w_hh0 = (const float*)d_in[2];
    const float* b_ih0 = (const float*)d_in[3];
    const float* b_hh0 = (const float*)d_in[4];
    const float* w_ih1 = (const float*)d_in[5];
    const float* w_hh1 = (const float*)d_in[6];
    const float* b_ih1 = (const float*)d_in[7];
    const float* b_hh1 = (const float*)d_in[8];
    const float* fc_w  = (const float*)d_in[9];
    const float* fc_b  = (const float*)d_in[10];
    float* out = (float*)d_out;

    const int B = in_sizes[0] / (TSTEPS * 4);   // 2048
    lstm_mfma<<<dim3(B / MB), dim3(BLK), 0, stream>>>(
        x, w_ih0, w_hh0, b_ih0, b_hh0, w_ih1, w_hh1, b_ih1, b_hh1, fc_w, fc_b, out);
}